// Round 8
// baseline (31.077 us; speedup 1.0000x reference)
//
#include <hip/hip_runtime.h>

constexpr int IMG_H = 2048;
constexpr int IMG_W = 2048;

// compare-exchange: a=min, b=max (2 VALU)
#define CE(a, b) {                                              \
    float _mn, _mx;                                             \
    asm("v_min_f32 %0, %1, %2" : "=v"(_mn) : "v"(a), "v"(b));   \
    asm("v_max_f32 %0, %1, %2" : "=v"(_mx) : "v"(a), "v"(b));   \
    a = _mn; b = _mx;                                           \
}

// 3-element sort via VOP3 3-input ops: a=min, b=med, c=max (3 VALU)
#define SORT3(a, b, c) {                                                      \
    float _n, _d, _x;                                                         \
    asm("v_min3_f32 %0, %1, %2, %3" : "=v"(_n) : "v"(a), "v"(b), "v"(c));     \
    asm("v_med3_f32 %0, %1, %2, %3" : "=v"(_d) : "v"(a), "v"(b), "v"(c));     \
    asm("v_max3_f32 %0, %1, %2, %3" : "=v"(_x) : "v"(a), "v"(b), "v"(c));     \
    a = _n; b = _d; c = _x;                                                   \
}

__device__ __forceinline__ void sw14(float& a0, float& a1, float& a2, float& a3, float& a4,
                                     float& a5, float& a6, float& a7, float& a8, float& a9,
                                     float& a10, float& a11, float& a12, float& a13) {
    SORT3(a0, a1, a2) SORT3(a3, a4, a5) SORT3(a6, a7, a8) SORT3(a9, a10, a11) CE(a12, a13)
    SORT3(a0, a3, a6) SORT3(a0, a9, a12)
    SORT3(a2, a5, a8) SORT3(a8, a11, a13)
}
__device__ __forceinline__ void sw13(float& a0, float& a1, float& a2, float& a3, float& a4,
                                     float& a5, float& a6, float& a7, float& a8, float& a9,
                                     float& a10, float& a11, float& a12) {
    SORT3(a0, a1, a2) SORT3(a3, a4, a5) SORT3(a6, a7, a8) SORT3(a9, a10, a11)
    SORT3(a0, a3, a6) SORT3(a0, a9, a12)
    SORT3(a2, a5, a8) SORT3(a8, a11, a12)
}
__device__ __forceinline__ void sw12(float& a0, float& a1, float& a2, float& a3, float& a4,
                                     float& a5, float& a6, float& a7, float& a8, float& a9,
                                     float& a10, float& a11) {
    SORT3(a0, a1, a2) SORT3(a3, a4, a5) SORT3(a6, a7, a8) SORT3(a9, a10, a11)
    SORT3(a0, a3, a6) CE(a0, a9)
    SORT3(a2, a5, a8) CE(a8, a11)
}
__device__ __forceinline__ void sw11(float& a0, float& a1, float& a2, float& a3, float& a4,
                                     float& a5, float& a6, float& a7, float& a8, float& a9,
                                     float& a10) {
    SORT3(a0, a1, a2) SORT3(a3, a4, a5) SORT3(a6, a7, a8) CE(a9, a10)
    SORT3(a0, a3, a6) CE(a0, a9)
    SORT3(a2, a5, a8) CE(a8, a10)
}
__device__ __forceinline__ void sw10(float& a0, float& a1, float& a2, float& a3, float& a4,
                                     float& a5, float& a6, float& a7, float& a8, float& a9) {
    SORT3(a0, a1, a2) SORT3(a3, a4, a5) SORT3(a6, a7, a8)
    SORT3(a0, a3, a6) CE(a0, a9)
    SORT3(a2, a5, a8) CE(a8, a9)
}
__device__ __forceinline__ void sw9(float& a0, float& a1, float& a2, float& a3, float& a4,
                                    float& a5, float& a6, float& a7, float& a8) {
    SORT3(a0, a1, a2) SORT3(a3, a4, a5) SORT3(a6, a7, a8)
    SORT3(a0, a3, a6)
    SORT3(a2, a5, a8)
}
__device__ __forceinline__ void sw8(float& a0, float& a1, float& a2, float& a3, float& a4,
                                    float& a5, float& a6, float& a7) {
    SORT3(a0, a1, a2) SORT3(a3, a4, a5) CE(a6, a7)
    SORT3(a0, a3, a6)
    SORT3(a2, a5, a7)
}
__device__ __forceinline__ void sw7(float& a0, float& a1, float& a2, float& a3, float& a4,
                                    float& a5, float& a6) {
    SORT3(a0, a1, a2) SORT3(a3, a4, a5)
    SORT3(a0, a3, a6)
    SORT3(a2, a5, a6)
}
__device__ __forceinline__ void sw6(float& a0, float& a1, float& a2, float& a3, float& a4,
                                    float& a5) {
    SORT3(a0, a1, a2) SORT3(a3, a4, a5)
    CE(a0, a3)
    CE(a2, a5)
}

__device__ __forceinline__ float med5(float l0, float l1, float l2, float l3, float l4) {
    CE(l0, l1) CE(l2, l3)
    float a, b;
    asm("v_max_f32 %0, %1, %2" : "=v"(a) : "v"(l0), "v"(l2));
    asm("v_min_f32 %0, %1, %2" : "=v"(b) : "v"(l1), "v"(l3));
    return __builtin_amdgcn_fmed3f(a, b, l4);
}

// tail for one pixel: 8 shared survivors (middle of shared 20) + 5 private -> median of 25
__device__ __forceinline__ float tail5(float l1, float l2, float l3, float l4, float l5,
                                       float l6, float l7, float l8,
                                       float p0, float p1, float p2, float p3, float p4) {
    float l0 = p0;
    sw9(l0, l1, l2, l3, l4, l5, l6, l7, l8);
    l0 = p1;
    sw8(l0, l1, l2, l3, l4, l5, l6, l7);
    l0 = p2;
    sw7(l0, l1, l2, l3, l4, l5, l6);
    l0 = p3;
    sw6(l0, l1, l2, l3, l4, l5);
    l0 = p4;
    return med5(l0, l1, l2, l3, l4);  // survivors are ranks 11..15 of 25
}

__global__ __launch_bounds__(256, 4) void median5x5_kernel(const float* __restrict__ img,
                                                           float* __restrict__ out) {
    const int t = blockIdx.x * blockDim.x + threadIdx.x;  // pixel-pair index
    const int y = blockIdx.y * blockDim.y + threadIdx.y;
    const int xL = 2 * t;  // left pixel; right = xL+1

    // reflected row bases
    int r0 = y - 2, r1 = y - 1, r3 = y + 1, r4 = y + 2;
    r0 = (r0 < 0) ? -r0 : r0;
    r1 = (r1 < 0) ? -r1 : r1;
    r3 = (r3 >= IMG_H) ? 2 * IMG_H - 2 - r3 : r3;
    r4 = (r4 >= IMG_H) ? 2 * IMG_H - 2 - r4 : r4;
    const int ry0 = r0 * IMG_W, ry1 = r1 * IMG_W, ry2 = y * IMG_W,
              ry3 = r3 * IMG_W, ry4 = r4 * IMG_W;

    // reflected column indices xL-2 .. xL+3
    int c0 = xL - 2, c1 = xL - 1, c4 = xL + 2, c5 = xL + 3;
    c0 = (c0 < 0) ? -c0 : c0;
    c1 = (c1 < 0) ? -c1 : c1;
    c4 = (c4 >= IMG_W) ? 2 * IMG_W - 2 - c4 : c4;
    c5 = (c5 >= IMG_W) ? 2 * IMG_W - 2 - c5 : c5;
    const int c2 = xL, c3 = xL + 1;

    // shared 20 = cols c1..c4 x 5 rows. First 14 into working set, 6 deferred.
    float w0 = img[ry0 + c1], w1 = img[ry0 + c2], w2 = img[ry0 + c3], w3 = img[ry0 + c4];
    float w4 = img[ry1 + c1], w5 = img[ry1 + c2], w6 = img[ry1 + c3], w7 = img[ry1 + c4];
    float w8 = img[ry2 + c1], w9 = img[ry2 + c2], w10 = img[ry2 + c3], w11 = img[ry2 + c4];
    float w12 = img[ry3 + c1], w13 = img[ry3 + c2];
    float e14 = img[ry3 + c3], e15 = img[ry3 + c4];
    float e16 = img[ry4 + c1], e17 = img[ry4 + c2], e18 = img[ry4 + c3], e19 = img[ry4 + c4];
    // private columns
    float p0 = img[ry0 + c0], p1 = img[ry1 + c0], p2 = img[ry2 + c0], p3 = img[ry3 + c0],
          p4 = img[ry4 + c0];
    float q0 = img[ry0 + c5], q1 = img[ry1 + c5], q2 = img[ry2 + c5], q3 = img[ry3 + c5],
          q4 = img[ry4 + c5];

    // REGISTER PIN: force all 30 window values to be simultaneously live here.
    // Compels the scheduler to hoist every load above the sort network (one
    // vmcnt drain) instead of interleaving loads just-in-time at ~28 VGPRs.
    asm(""
        : "+v"(w0), "+v"(w1), "+v"(w2), "+v"(w3), "+v"(w4), "+v"(w5), "+v"(w6),
          "+v"(w7), "+v"(w8), "+v"(w9), "+v"(w10), "+v"(w11), "+v"(w12), "+v"(w13),
          "+v"(e14), "+v"(e15), "+v"(e16), "+v"(e17), "+v"(e18), "+v"(e19),
          "+v"(p0), "+v"(p1), "+v"(p2), "+v"(p3), "+v"(p4),
          "+v"(q0), "+v"(q1), "+v"(q2), "+v"(q3), "+v"(q4));

    // shared forgetful phase: sweeps 14..9 over the 20 shared elements.
    sw14(w0, w1, w2, w3, w4, w5, w6, w7, w8, w9, w10, w11, w12, w13);
    w0 = e14;
    sw13(w0, w1, w2, w3, w4, w5, w6, w7, w8, w9, w10, w11, w12);
    w0 = e15;
    sw12(w0, w1, w2, w3, w4, w5, w6, w7, w8, w9, w10, w11);
    w0 = e16;
    sw11(w0, w1, w2, w3, w4, w5, w6, w7, w8, w9, w10);
    w0 = e17;
    sw10(w0, w1, w2, w3, w4, w5, w6, w7, w8, w9);
    w0 = e18;
    sw9(w0, w1, w2, w3, w4, w5, w6, w7, w8);
    w0 = e19;
    // survivors {w0..w7} = middle 8 (ranks 7..14) of the shared 20

    const float medL = tail5(w0, w1, w2, w3, w4, w5, w6, w7, p0, p1, p2, p3, p4);
    const float medR = tail5(w0, w1, w2, w3, w4, w5, w6, w7, q0, q1, q2, q3, q4);

    float2 res = make_float2(medL, medR);
    *reinterpret_cast<float2*>(out + ry2 + xL) = res;
}

extern "C" void kernel_launch(void* const* d_in, const int* in_sizes, int n_in,
                              void* d_out, int out_size, void* d_ws, size_t ws_size,
                              hipStream_t stream) {
    const float* img = (const float*)d_in[0];
    float* out = (float*)d_out;
    dim3 block(64, 4);
    dim3 grid((IMG_W / 2) / 64, IMG_H / 4);
    median5x5_kernel<<<grid, block, 0, stream>>>(img, out);
}

// Round 9
// 22.419 us; speedup vs baseline: 1.3862x; 1.3862x over previous
//
#include <hip/hip_runtime.h>

constexpr int IMG_H = 2048;
constexpr int IMG_W = 2048;
constexpr int P = 8;  // output rows per thread

// compare-exchange: a=min, b=max (2 VALU)
#define CE(a, b) {                                              \
    float _mn, _mx;                                             \
    asm("v_min_f32 %0, %1, %2" : "=v"(_mn) : "v"(a), "v"(b));   \
    asm("v_max_f32 %0, %1, %2" : "=v"(_mx) : "v"(a), "v"(b));   \
    a = _mn; b = _mx;                                           \
}

// 3-element sort via VOP3 3-input ops: a=min, b=med, c=max (3 VALU)
#define SORT3(a, b, c) {                                                      \
    float _n, _d, _x;                                                         \
    asm("v_min3_f32 %0, %1, %2, %3" : "=v"(_n) : "v"(a), "v"(b), "v"(c));     \
    asm("v_med3_f32 %0, %1, %2, %3" : "=v"(_d) : "v"(a), "v"(b), "v"(c));     \
    asm("v_max3_f32 %0, %1, %2, %3" : "=v"(_x) : "v"(a), "v"(b), "v"(c));     \
    a = _n; b = _d; c = _x;                                                   \
}

__device__ __forceinline__ void sw14(float& a0, float& a1, float& a2, float& a3, float& a4,
                                     float& a5, float& a6, float& a7, float& a8, float& a9,
                                     float& a10, float& a11, float& a12, float& a13) {
    SORT3(a0, a1, a2) SORT3(a3, a4, a5) SORT3(a6, a7, a8) SORT3(a9, a10, a11) CE(a12, a13)
    SORT3(a0, a3, a6) SORT3(a0, a9, a12)
    SORT3(a2, a5, a8) SORT3(a8, a11, a13)
}
__device__ __forceinline__ void sw13(float& a0, float& a1, float& a2, float& a3, float& a4,
                                     float& a5, float& a6, float& a7, float& a8, float& a9,
                                     float& a10, float& a11, float& a12) {
    SORT3(a0, a1, a2) SORT3(a3, a4, a5) SORT3(a6, a7, a8) SORT3(a9, a10, a11)
    SORT3(a0, a3, a6) SORT3(a0, a9, a12)
    SORT3(a2, a5, a8) SORT3(a8, a11, a12)
}
__device__ __forceinline__ void sw12(float& a0, float& a1, float& a2, float& a3, float& a4,
                                     float& a5, float& a6, float& a7, float& a8, float& a9,
                                     float& a10, float& a11) {
    SORT3(a0, a1, a2) SORT3(a3, a4, a5) SORT3(a6, a7, a8) SORT3(a9, a10, a11)
    SORT3(a0, a3, a6) CE(a0, a9)
    SORT3(a2, a5, a8) CE(a8, a11)
}
__device__ __forceinline__ void sw11(float& a0, float& a1, float& a2, float& a3, float& a4,
                                     float& a5, float& a6, float& a7, float& a8, float& a9,
                                     float& a10) {
    SORT3(a0, a1, a2) SORT3(a3, a4, a5) SORT3(a6, a7, a8) CE(a9, a10)
    SORT3(a0, a3, a6) CE(a0, a9)
    SORT3(a2, a5, a8) CE(a8, a10)
}
__device__ __forceinline__ void sw10(float& a0, float& a1, float& a2, float& a3, float& a4,
                                     float& a5, float& a6, float& a7, float& a8, float& a9) {
    SORT3(a0, a1, a2) SORT3(a3, a4, a5) SORT3(a6, a7, a8)
    SORT3(a0, a3, a6) CE(a0, a9)
    SORT3(a2, a5, a8) CE(a8, a9)
}
__device__ __forceinline__ void sw9(float& a0, float& a1, float& a2, float& a3, float& a4,
                                    float& a5, float& a6, float& a7, float& a8) {
    SORT3(a0, a1, a2) SORT3(a3, a4, a5) SORT3(a6, a7, a8)
    SORT3(a0, a3, a6)
    SORT3(a2, a5, a8)
}
__device__ __forceinline__ void sw8(float& a0, float& a1, float& a2, float& a3, float& a4,
                                    float& a5, float& a6, float& a7) {
    SORT3(a0, a1, a2) SORT3(a3, a4, a5) CE(a6, a7)
    SORT3(a0, a3, a6)
    SORT3(a2, a5, a7)
}
__device__ __forceinline__ void sw7(float& a0, float& a1, float& a2, float& a3, float& a4,
                                    float& a5, float& a6) {
    SORT3(a0, a1, a2) SORT3(a3, a4, a5)
    SORT3(a0, a3, a6)
    SORT3(a2, a5, a6)
}
__device__ __forceinline__ void sw6(float& a0, float& a1, float& a2, float& a3, float& a4,
                                    float& a5) {
    SORT3(a0, a1, a2) SORT3(a3, a4, a5)
    CE(a0, a3)
    CE(a2, a5)
}

__device__ __forceinline__ float med5(float l0, float l1, float l2, float l3, float l4) {
    CE(l0, l1) CE(l2, l3)
    float a, b;
    asm("v_max_f32 %0, %1, %2" : "=v"(a) : "v"(l0), "v"(l2));
    asm("v_min_f32 %0, %1, %2" : "=v"(b) : "v"(l1), "v"(l3));
    return __builtin_amdgcn_fmed3f(a, b, l4);
}

// tail: 8 shared survivors + 5 private column values -> exact median of 25
__device__ __forceinline__ float tail5(float l1, float l2, float l3, float l4, float l5,
                                       float l6, float l7, float l8,
                                       float p0, float p1, float p2, float p3, float p4) {
    float l0 = p0;
    sw9(l0, l1, l2, l3, l4, l5, l6, l7, l8);
    l0 = p1;
    sw8(l0, l1, l2, l3, l4, l5, l6, l7);
    l0 = p2;
    sw7(l0, l1, l2, l3, l4, l5, l6);
    l0 = p3;
    sw6(l0, l1, l2, l3, l4, l5);
    l0 = p4;
    return med5(l0, l1, l2, l3, l4);
}

// shared forgetful phase over 20 elements (4 shared cols x 5 rows) -> middle 8.
// Takes by value; preserves the caller's row registers.
__device__ __forceinline__ void shared20(float s0, float s1, float s2, float s3, float s4,
                                         float s5, float s6, float s7, float s8, float s9,
                                         float s10, float s11, float s12, float s13,
                                         float s14, float s15, float s16, float s17,
                                         float s18, float s19,
                                         float& o0, float& o1, float& o2, float& o3,
                                         float& o4, float& o5, float& o6, float& o7) {
    sw14(s0, s1, s2, s3, s4, s5, s6, s7, s8, s9, s10, s11, s12, s13);
    s0 = s14;
    sw13(s0, s1, s2, s3, s4, s5, s6, s7, s8, s9, s10, s11, s12);
    s0 = s15;
    sw12(s0, s1, s2, s3, s4, s5, s6, s7, s8, s9, s10, s11);
    s0 = s16;
    sw11(s0, s1, s2, s3, s4, s5, s6, s7, s8, s9, s10);
    s0 = s17;
    sw10(s0, s1, s2, s3, s4, s5, s6, s7, s8, s9);
    s0 = s18;
    sw9(s0, s1, s2, s3, s4, s5, s6, s7, s8);
    s0 = s19;
    o0 = s0; o1 = s1; o2 = s2; o3 = s3; o4 = s4; o5 = s5; o6 = s6; o7 = s7;
}

__device__ __forceinline__ int rowbase(int r) {
    r = (r < 0) ? -r : r;
    r = (r >= IMG_H) ? 2 * IMG_H - 2 - r : r;
    return r * IMG_W;
}

// load one window row (6 reflected columns) into named registers R0..R5
#define LOADR(R, rb) {                                        \
    const int _b = (rb);                                      \
    R##0 = img[_b + c0]; R##1 = img[_b + c1];                 \
    R##2 = img[_b + c2]; R##3 = img[_b + c3];                 \
    R##4 = img[_b + c4]; R##5 = img[_b + c5];                 \
}

// one output row: prefetch row (yy)+3 into Rf, compute median row yy from Ra..Re
#define STEP(Ra, Rb, Rc, Rd, Re, Rf, yy) {                                     \
    LOADR(Rf, rowbase((yy) + 3))                                               \
    float u0, u1, u2, u3, u4, u5, u6, u7;                                      \
    shared20(Ra##1, Ra##2, Ra##3, Ra##4, Rb##1, Rb##2, Rb##3, Rb##4,           \
             Rc##1, Rc##2, Rc##3, Rc##4, Rd##1, Rd##2, Rd##3, Rd##4,           \
             Re##1, Re##2, Re##3, Re##4, u0, u1, u2, u3, u4, u5, u6, u7);      \
    const float _mL = tail5(u0, u1, u2, u3, u4, u5, u6, u7,                    \
                            Ra##0, Rb##0, Rc##0, Rd##0, Re##0);                \
    const float _mR = tail5(u0, u1, u2, u3, u4, u5, u6, u7,                    \
                            Ra##5, Rb##5, Rc##5, Rd##5, Re##5);                \
    *reinterpret_cast<float2*>(out + (yy) * IMG_W + xL) = make_float2(_mL, _mR); \
}

__global__ __launch_bounds__(256) void median5x5_strip(const float* __restrict__ img,
                                                       float* __restrict__ out) {
    const int t = blockIdx.x * blockDim.x + threadIdx.x;      // pair-column 0..1023
    const int strip = blockIdx.y * blockDim.y + threadIdx.y;  // 0..255
    const int y0 = strip * P;
    const int xL = 2 * t;

    // reflected column indices xL-2 .. xL+3 (constant over the strip)
    int c0 = xL - 2, c1 = xL - 1, c4 = xL + 2, c5 = xL + 3;
    c0 = (c0 < 0) ? -c0 : c0;
    c1 = (c1 < 0) ? -c1 : c1;
    c4 = (c4 >= IMG_W) ? 2 * IMG_W - 2 - c4 : c4;
    c5 = (c5 >= IMG_W) ? 2 * IMG_W - 2 - c5 : c5;
    const int c2 = xL, c3 = xL + 1;

    // sliding 5-row x 6-col register window across 6 row buffers A..F
    float A0, A1, A2, A3, A4, A5;
    float B0, B1, B2, B3, B4, B5;
    float C0, C1, C2, C3, C4, C5;
    float D0, D1, D2, D3, D4, D5;
    float E0, E1, E2, E3, E4, E5;
    float F0, F1, F2, F3, F4, F5;

    // prologue: rows y0-2 .. y0+2
    LOADR(A, rowbase(y0 - 2))
    LOADR(B, rowbase(y0 - 1))
    LOADR(C, rowbase(y0))
    LOADR(D, rowbase(y0 + 1))
    LOADR(E, rowbase(y0 + 2))

    STEP(A, B, C, D, E, F, y0 + 0)
    STEP(B, C, D, E, F, A, y0 + 1)
    STEP(C, D, E, F, A, B, y0 + 2)
    STEP(D, E, F, A, B, C, y0 + 3)
    STEP(E, F, A, B, C, D, y0 + 4)
    STEP(F, A, B, C, D, E, y0 + 5)
    STEP(A, B, C, D, E, F, y0 + 6)
    STEP(B, C, D, E, F, A, y0 + 7)
}

extern "C" void kernel_launch(void* const* d_in, const int* in_sizes, int n_in,
                              void* d_out, int out_size, void* d_ws, size_t ws_size,
                              hipStream_t stream) {
    const float* img = (const float*)d_in[0];
    float* out = (float*)d_out;
    dim3 block(64, 4);
    dim3 grid((IMG_W / 2) / 64, IMG_H / P / 4);
    median5x5_strip<<<grid, block, 0, stream>>>(img, out);
}